// Round 1
// baseline (10606.274 us; speedup 1.0000x reference)
//
#include <hip/hip_runtime.h>

#define NB    4
#define H     512
#define W     512
#define C     3
#define ITERS 30
#define TOLF  1e-05f
#define TOTAL (NB*H*W*C)   // 3,145,728
#define BLK   256
#define NBLKS (TOTAL / BLK) // 12288, exact

__device__ __forceinline__ int reflect_idx(int v, int n) {
    if (v < 0)  return -v;
    if (v >= n) return 2 * n - 2 - v;
    return v;
}

__device__ __forceinline__ float conv9(const float* __restrict__ src,
                                       const float* __restrict__ k,
                                       int n, int y, int x, int c) {
    float acc = 0.0f;
#pragma unroll
    for (int dy = -1; dy <= 1; ++dy) {
        const int ry = reflect_idx(y + dy, H);
#pragma unroll
        for (int dx = -1; dx <= 1; ++dx) {
            const int rx = reflect_idx(x + dx, W);
            const float v  = src[((n * H + ry) * W + rx) * C + c];
            const float kv = k[((dy + 1) * 3 + (dx + 1)) * C + c];
            acc = fmaf(v, kv, acc);
        }
    }
    return acc;
}

// Kernel A: rb = inputs / conv(latent, kernel)
__global__ __launch_bounds__(BLK) void rl_convA(const float* __restrict__ latent,
                                                const float* __restrict__ inputs,
                                                const float* __restrict__ k,
                                                float* __restrict__ rb) {
    const int idx = blockIdx.x * BLK + threadIdx.x;
    if (idx >= TOTAL) return;
    int t = idx;
    const int c = t % C; t /= C;
    const int x = t % W; t /= W;
    const int y = t % H;
    const int n = t / H;
    const float est = conv9(latent, k, n, y, x, c);
    rb[idx] = inputs[idx] / est;
}

// Kernel B: e = conv(rb, kf); if (!done) latent *= e; reduce sum(e); last block
// finalizes: done |= |1 - mean| < TOL, resets accumulators for next iteration.
__global__ __launch_bounds__(BLK) void rl_convB(const float* __restrict__ rb,
                                                const float* __restrict__ kf,
                                                float* __restrict__ latent,
                                                double* __restrict__ sum,
                                                int* __restrict__ done,
                                                unsigned int* __restrict__ count) {
    __shared__ float wave_sums[BLK / 64];
    __shared__ int   s_done;

    const int idx = blockIdx.x * BLK + threadIdx.x;
    if (threadIdx.x == 0) s_done = *done;   // visible from prior kernel (dispatch boundary)
    __syncthreads();

    int t = idx;
    const int c = t % C; t /= C;
    const int x = t % W; t /= W;
    const int y = t % H;
    const int n = t / H;

    const float e = conv9(rb, kf, n, y, x, c);
    if (!s_done) latent[idx] = latent[idx] * e;

    // wave (64-lane) shuffle reduction, then cross-wave via LDS
    float v = e;
#pragma unroll
    for (int off = 32; off > 0; off >>= 1) v += __shfl_down(v, off, 64);
    if ((threadIdx.x & 63) == 0) wave_sums[threadIdx.x >> 6] = v;
    __syncthreads();

    if (threadIdx.x == 0) {
        float bsum = 0.0f;
#pragma unroll
        for (int i = 0; i < BLK / 64; ++i) bsum += wave_sums[i];
        atomicAdd(sum, (double)bsum);           // device-scope
        __threadfence();
        const unsigned int old = atomicAdd(count, 1u);
        if (old == (unsigned int)(gridDim.x - 1)) {
            // all blocks' sum contributions are in (each incremented count after its add)
            const double s = atomicAdd(sum, 0.0);               // coherent read
            const float mean = (float)(s / (double)TOTAL);
            const float diff = fabsf(1.0f - mean);
            if (diff < TOLF) *done = 1;                          // consumed next launch
            atomicExch((unsigned long long*)sum, 0ull);          // reset accumulator
            atomicExch(count, 0u);                               // reset counter
        }
    }
}

extern "C" void kernel_launch(void* const* d_in, const int* in_sizes, int n_in,
                              void* d_out, int out_size, void* d_ws, size_t ws_size,
                              hipStream_t stream) {
    const float* inputs = (const float*)d_in[0];
    const float* kern   = (const float*)d_in[1];
    const float* kernf  = (const float*)d_in[2];
    float* latent = (float*)d_out;

    // ws layout: [0..7] double sum | [8..11] int done | [12..15] uint count | 256.. rb buffer
    char* ws = (char*)d_ws;
    double*       sum   = (double*)(ws + 0);
    int*          done  = (int*)(ws + 8);
    unsigned int* count = (unsigned int*)(ws + 12);
    float*        rb    = (float*)(ws + 256);

    // zero scalars (ws is poisoned 0xAA before every timed call)
    hipMemsetAsync(d_ws, 0, 256, stream);
    // latent <- inputs
    hipMemcpyAsync(latent, inputs, (size_t)TOTAL * sizeof(float),
                   hipMemcpyDeviceToDevice, stream);

    for (int it = 0; it < ITERS; ++it) {
        rl_convA<<<NBLKS, BLK, 0, stream>>>(latent, inputs, kern, rb);
        rl_convB<<<NBLKS, BLK, 0, stream>>>(rb, kernf, latent, sum, done, count);
    }
}

// Round 2
// 1057.855 us; speedup vs baseline: 10.0262x; 10.0262x over previous
//
#include <hip/hip_runtime.h>

#define NB    4
#define H     512
#define W     512
#define C     3
#define ITERS 30
#define TOLF  1e-05f
#define TOTAL (NB*H*W*C)    // 3,145,728
#define BLK   256
#define NBLKS (TOTAL / BLK) // 12288, exact

__device__ __forceinline__ int reflect_idx(int v, int n) {
    if (v < 0)  return -v;
    if (v >= n) return 2 * n - 2 - v;
    return v;
}

__device__ __forceinline__ float conv9(const float* __restrict__ src,
                                       const float* __restrict__ k,
                                       int n, int y, int x, int c) {
    float acc = 0.0f;
#pragma unroll
    for (int dy = -1; dy <= 1; ++dy) {
        const int ry = reflect_idx(y + dy, H);
#pragma unroll
        for (int dx = -1; dx <= 1; ++dx) {
            const int rx = reflect_idx(x + dx, W);
            const float v  = src[((n * H + ry) * W + rx) * C + c];
            const float kv = k[((dy + 1) * 3 + (dx + 1)) * C + c];
            acc = fmaf(v, kv, acc);
        }
    }
    return acc;
}

// Kernel A: rb = inputs / conv(latent, kernel).
// Side job (block 0, when do_finalize): sum partials from previous convB,
// update `done`. No atomics anywhere — kernel-boundary coherence only.
__global__ __launch_bounds__(BLK) void rl_convA(const float* __restrict__ latent,
                                                const float* __restrict__ inputs,
                                                const float* __restrict__ k,
                                                float* __restrict__ rb,
                                                const float* __restrict__ partials,
                                                int* __restrict__ done,
                                                int do_finalize) {
    __shared__ double fin_sums[BLK / 64];

    if (do_finalize && blockIdx.x == 0) {
        double acc = 0.0;
        for (int i = threadIdx.x; i < NBLKS; i += BLK) acc += (double)partials[i];
#pragma unroll
        for (int off = 32; off > 0; off >>= 1) acc += __shfl_down(acc, off, 64);
        if ((threadIdx.x & 63) == 0) fin_sums[threadIdx.x >> 6] = acc;
        __syncthreads();
        if (threadIdx.x == 0) {
            const double s = fin_sums[0] + fin_sums[1] + fin_sums[2] + fin_sums[3];
            const float mean = (float)(s / (double)TOTAL);
            if (fabsf(1.0f - mean) < TOLF) *done = 1;   // consumed by next convB
        }
    }

    const int idx = blockIdx.x * BLK + threadIdx.x;
    int t = idx;
    const int c = t % C; t /= C;
    const int x = t % W; t /= W;
    const int y = t % H;
    const int n = t / H;
    const float est = conv9(latent, k, n, y, x, c);
    rb[idx] = inputs[idx] / est;
}

// Kernel B: e = conv(rb, kf); if (!done) latent *= e;
// block-reduce e and store the partial with a PLAIN store (no atomic/fence).
__global__ __launch_bounds__(BLK) void rl_convB(const float* __restrict__ rb,
                                                const float* __restrict__ kf,
                                                float* __restrict__ latent,
                                                float* __restrict__ partials,
                                                const int* __restrict__ done) {
    __shared__ float wave_sums[BLK / 64];
    __shared__ int   s_done;

    const int idx = blockIdx.x * BLK + threadIdx.x;
    if (threadIdx.x == 0) s_done = *done;   // written by a PREVIOUS dispatch only
    __syncthreads();

    int t = idx;
    const int c = t % C; t /= C;
    const int x = t % W; t /= W;
    const int y = t % H;
    const int n = t / H;

    const float e = conv9(rb, kf, n, y, x, c);
    if (!s_done) latent[idx] = latent[idx] * e;

    float v = e;
#pragma unroll
    for (int off = 32; off > 0; off >>= 1) v += __shfl_down(v, off, 64);
    if ((threadIdx.x & 63) == 0) wave_sums[threadIdx.x >> 6] = v;
    __syncthreads();

    if (threadIdx.x == 0) {
        float bsum = 0.0f;
#pragma unroll
        for (int i = 0; i < BLK / 64; ++i) bsum += wave_sums[i];
        partials[blockIdx.x] = bsum;        // plain store — no contention
    }
}

extern "C" void kernel_launch(void* const* d_in, const int* in_sizes, int n_in,
                              void* d_out, int out_size, void* d_ws, size_t ws_size,
                              hipStream_t stream) {
    const float* inputs = (const float*)d_in[0];
    const float* kern   = (const float*)d_in[1];
    const float* kernf  = (const float*)d_in[2];
    float* latent = (float*)d_out;

    // ws layout: [0..255] scalars (done at +0) | partials (12288 f32) | rb
    char* ws = (char*)d_ws;
    int*   done     = (int*)(ws + 0);
    float* partials = (float*)(ws + 256);
    float* rb       = (float*)(ws + 256 + NBLKS * sizeof(float)); // 256-aligned

    hipMemsetAsync(d_ws, 0, 256, stream);   // done = 0
    hipMemcpyAsync(latent, inputs, (size_t)TOTAL * sizeof(float),
                   hipMemcpyDeviceToDevice, stream);

    for (int it = 0; it < ITERS; ++it) {
        rl_convA<<<NBLKS, BLK, 0, stream>>>(latent, inputs, kern, rb,
                                            partials, done, it > 0 ? 1 : 0);
        rl_convB<<<NBLKS, BLK, 0, stream>>>(rb, kernf, latent, partials, done);
    }
}

// Round 3
// 671.061 us; speedup vs baseline: 15.8052x; 1.5764x over previous
//
#include <hip/hip_runtime.h>

#define NB    4
#define H     512
#define W     512
#define C     3
#define ITERS 30
#define TOLF  1e-05f
#define TOTAL (NB*H*W*C)     // 3,145,728
#define BLK   256
#define TX    32
#define TY    32
#define GX    (W/TX)         // 16
#define GY    (H/TY)         // 16
#define NBLKS (NB*GX*GY)     // 1024
#define LTW   (TX+4)         // 36
#define LTH   (TY+4)         // 36
#define RW    (TX+2)         // 34
#define RH    (TY+2)         // 34
#define LAT_N (LTH*LTW*C)    // 3888
#define RB_N  (RH*RW*C)      // 3468
#define OUT_N (TY*TX*C)      // 3072

__device__ __forceinline__ int refl(int v, int n) {
    if (v < 0)  return -v;
    if (v >= n) return 2 * n - 2 - v;
    return v;
}

// One RL iteration, fully fused:
//   rb = inputs / conv(latent, k)   (computed into LDS, halo 1, reflect-aware)
//   e  = conv(rb, kf)
//   latent *= e (gated on cumulative done), partials[b] = block-sum(e)
// done decision for THIS iteration is recomputed redundantly by every block
// from the previous dispatch's partials (deterministic fixed-order sum).
__global__ __launch_bounds__(BLK) void rl_fused(
    const float* __restrict__ lat_src,   // latent (== inputs at it 0)
    const float* __restrict__ inputs,
    const float* __restrict__ gk,
    const float* __restrict__ gkf,
    float* __restrict__ lat_out,
    float* __restrict__ partials,
    int* __restrict__ done,
    int do_check)
{
    __shared__ float  lat[LAT_N];
    __shared__ float  rbt[RB_N];
    __shared__ float  kk[27], kkf[27];
    __shared__ double red[BLK / 64];
    __shared__ float  wred[BLK / 64];
    __shared__ int    s_done;

    const int tid = threadIdx.x;
    const int b   = blockIdx.x;
    const int n   = b / (GX * GY);
    const int r   = b % (GX * GY);
    const int ty0 = (r / GX) * TY;
    const int tx0 = (r % GX) * TX;

    // stage conv kernels into LDS
    if (tid < 27)       kk[tid]        = gk[tid];
    else if (tid < 54)  kkf[tid - 27]  = gkf[tid - 27];

    // cumulative done flag: global flag (dispatches < it-1) OR diff_{it-1}
    if (do_check) {
        if (tid == 0) s_done = *done;
        double a = 0.0;
        for (int i = tid; i < NBLKS; i += BLK) a += (double)partials[i];
        #pragma unroll
        for (int off = 32; off; off >>= 1) a += __shfl_down(a, off, 64);
        if ((tid & 63) == 0) red[tid >> 6] = a;
        __syncthreads();
        if (tid == 0) {
            const double s = red[0] + red[1] + red[2] + red[3];
            const float mean = (float)(s / (double)TOTAL);
            if (fabsf(1.0f - mean) < TOLF) { s_done = 1; *done = 1; }
        }
    } else {
        if (tid == 0) { s_done = 0; *done = 0; }  // it 0: init (ws is poisoned)
    }

    // stage latent tile, halo 2, reflect applied at load
    const float* src_n = lat_src + (size_t)n * H * W * C;
    for (int l = tid; l < LAT_N; l += BLK) {
        const int c = l % C;
        const int t2 = l / C;
        const int j = t2 % LTW;
        const int i = t2 / LTW;
        const int gy = refl(ty0 - 2 + i, H);
        const int gx = refl(tx0 - 2 + j, W);
        lat[l] = src_n[(gy * W + gx) * C + c];
    }
    __syncthreads();

    // rb tile, halo 1: rb(p) = inputs(refl p) / conv(lat)(refl p)
    const float* inp_n = inputs + (size_t)n * H * W * C;
    for (int l = tid; l < RB_N; l += BLK) {
        const int c = l % C;
        const int t2 = l / C;
        const int j = t2 % RW;
        const int i = t2 / RW;
        const int ry = refl(ty0 - 1 + i, H);
        const int rx = refl(tx0 - 1 + j, W);
        const int ti = ry - ty0 + 2;
        const int tj = rx - tx0 + 2;
        float acc = 0.0f;
        #pragma unroll
        for (int dy = -1; dy <= 1; ++dy)
            #pragma unroll
            for (int dx = -1; dx <= 1; ++dx)
                acc = fmaf(lat[((ti + dy) * LTW + (tj + dx)) * C + c],
                           kk[((dy + 1) * 3 + (dx + 1)) * C + c], acc);
        rbt[l] = inp_n[(ry * W + rx) * C + c] / acc;
    }
    __syncthreads();

    // output tile: e = conv(rbt, kf); latent *= e
    float esum = 0.0f;
    float* out_n = lat_out + (size_t)n * H * W * C;
    for (int l = tid; l < OUT_N; l += BLK) {
        const int c = l % C;
        const int t2 = l / C;
        const int j = t2 % TX;
        const int i = t2 / TX;
        float e = 0.0f;
        #pragma unroll
        for (int dy = -1; dy <= 1; ++dy)
            #pragma unroll
            for (int dx = -1; dx <= 1; ++dx)
                e = fmaf(rbt[((i + 1 + dy) * RW + (j + 1 + dx)) * C + c],
                         kkf[((dy + 1) * 3 + (dx + 1)) * C + c], e);
        esum += e;
        if (!s_done)
            out_n[((ty0 + i) * W + (tx0 + j)) * C + c] =
                lat[((i + 2) * LTW + (j + 2)) * C + c] * e;
    }

    // block-reduce esum -> partials[b] (plain store)
    #pragma unroll
    for (int off = 32; off; off >>= 1) esum += __shfl_down(esum, off, 64);
    if ((tid & 63) == 0) wred[tid >> 6] = esum;
    __syncthreads();
    if (tid == 0) partials[b] = wred[0] + wred[1] + wred[2] + wred[3];
}

extern "C" void kernel_launch(void* const* d_in, const int* in_sizes, int n_in,
                              void* d_out, int out_size, void* d_ws, size_t ws_size,
                              hipStream_t stream) {
    const float* inputs = (const float*)d_in[0];
    const float* kern   = (const float*)d_in[1];
    const float* kernf  = (const float*)d_in[2];
    float* latent = (float*)d_out;

    // ws layout: [0..3] done flag | [256..] partials (1024 f32)
    char* ws = (char*)d_ws;
    int*   done     = (int*)(ws + 0);
    float* partials = (float*)(ws + 256);

    for (int it = 0; it < ITERS; ++it) {
        const float* lat_src = (it == 0) ? inputs : latent;
        rl_fused<<<NBLKS, BLK, 0, stream>>>(lat_src, inputs, kern, kernf,
                                            latent, partials, done,
                                            it > 0 ? 1 : 0);
    }
}

// Round 4
// 644.569 us; speedup vs baseline: 16.4548x; 1.0411x over previous
//
#include <hip/hip_runtime.h>

#define NB    4
#define H     512
#define W     512
#define C     3
#define ITERS 30
#define TOLF  1e-05f
#define TOTAL (NB*H*W*C)     // 3,145,728
#define BLK   256
#define TX    32
#define TY    32
#define GX    (W/TX)         // 16
#define GY    (H/TY)         // 16
#define NBLKS (NB*GX*GY)     // 1024
#define LRS   36             // lat tile row stride (floats)
#define LPS   (36*36)        // lat plane stride
#define RRS   34             // rb tile row stride
#define RPS   (34*34)        // rb plane stride

__device__ __forceinline__ int refl(int v, int n) {
    if (v < 0)  return -v;
    if (v >= n) return 2 * n - 2 - v;
    return v;
}

// One fused RL iteration. Planar LDS tiles, reflect materialized by in-LDS
// fixups, 2x2-pixel register blocking in both conv stages, kernel weights as
// wave-uniform scalar loads, rcp instead of div.
__global__ __launch_bounds__(BLK) void rl_fused(
    const float* __restrict__ lat_src,
    const float* __restrict__ inputs,
    const float* __restrict__ gk,
    const float* __restrict__ gkf,
    float* __restrict__ lat_out,
    const float* __restrict__ part_rd,   // partials from PREVIOUS dispatch
    float* __restrict__ part_wr,         // partials for NEXT dispatch
    int* __restrict__ done,
    int do_check)
{
    __shared__ float  lat[3 * LPS];
    __shared__ float  rbt[3 * RPS];
    __shared__ double red[BLK / 64];
    __shared__ float  wred[BLK / 64];
    __shared__ int    s_done;

    const int tid  = threadIdx.x;
    const int lane = tid & 63;
    const int wid  = tid >> 6;
    const int b    = blockIdx.x;
    const int n    = b >> 8;           // GX*GY == 256
    const int r    = b & 255;
    const int ty0  = (r >> 4) << 5;
    const int tx0  = (r & 15) << 5;

    // ---- cumulative done flag (redundant per block, deterministic) ----
    if (do_check) {
        if (tid == 0) s_done = *done;
        double a = 0.0;
        #pragma unroll
        for (int i = 0; i < NBLKS / BLK; ++i) a += (double)part_rd[tid + i * BLK];
        #pragma unroll
        for (int off = 32; off; off >>= 1) a += __shfl_down(a, off, 64);
        if (lane == 0) red[wid] = a;
        __syncthreads();
        if (tid == 0) {
            const double s = red[0] + red[1] + red[2] + red[3];
            const float mean = (float)(s / (double)TOTAL);
            if (fabsf(1.0f - mean) < TOLF) { s_done = 1; *done = 1; }
        }
    } else {
        if (tid == 0) { s_done = 0; *done = 0; }
    }

    // ---- stage latent tile (planar), in-bounds region only ----
    const float* src_n = lat_src + (size_t)n * (H * W * C);
    const float* inp_n = inputs  + (size_t)n * (H * W * C);

    const int gx_lo = (tx0 == 0) ? 0 : tx0 - 2;
    const int gx_hi = (tx0 + TX == W) ? W - 1 : tx0 + TX + 1;
    const int lx0   = gx_lo - (tx0 - 2);          // 0 or 2
    const int nflt  = (gx_hi - gx_lo + 1) * 3;    // 108 or 102
    const int i_lo  = (ty0 == 0) ? 2 : 0;
    const int i_hi  = (ty0 + TY == H) ? 33 : 35;

    for (int i = i_lo + wid; i <= i_hi; i += BLK / 64) {
        const int gy = ty0 - 2 + i;
        const float* srow = src_n + ((size_t)gy * W + gx_lo) * 3;
        const int base = i * LRS + lx0;
        for (int f = lane; f < nflt; f += 64) {
            const int j = f / 3;              // const divisor -> magic mul
            const int c = f - j * 3;
            lat[c * LPS + base + j] = srow[f];
        }
    }
    __syncthreads();

    // ---- column reflect fixup (in-LDS) ----
    if (tx0 == 0) {
        for (int t = tid; t < 36 * 6; t += BLK) {
            const int i = t / 6, rr = t % 6;
            const int c = rr >> 1, col = rr & 1;          // cols 0,1 <- 4,3
            lat[c * LPS + i * LRS + col] = lat[c * LPS + i * LRS + (4 - col)];
        }
    } else if (tx0 + TX == W) {
        for (int t = tid; t < 36 * 6; t += BLK) {
            const int i = t / 6, rr = t % 6;
            const int c = rr >> 1, col = rr & 1;          // cols 34,35 <- 32,31
            lat[c * LPS + i * LRS + 34 + col] = lat[c * LPS + i * LRS + (32 - col)];
        }
    }
    __syncthreads();

    // ---- row reflect fixup (after columns: corners correct) ----
    if (ty0 == 0) {
        for (int t = tid; t < 3 * 2 * 36; t += BLK) {
            const int c = t / 72, rr = t % 72;
            const int row = rr / 36, j = rr % 36;         // rows 0,1 <- 4,3
            lat[c * LPS + row * LRS + j] = lat[c * LPS + (4 - row) * LRS + j];
        }
    } else if (ty0 + TY == H) {
        for (int t = tid; t < 3 * 2 * 36; t += BLK) {
            const int c = t / 72, rr = t % 72;
            const int row = rr / 36, j = rr % 36;         // rows 34,35 <- 32,31
            lat[c * LPS + (34 + row) * LRS + j] = lat[c * LPS + (32 - row) * LRS + j];
        }
    }
    __syncthreads();

    // ---- rb stage: 17x17 grid of 2x2 pixel blocks ----
    const bool ye0 = (ty0 == 0), ye1 = (ty0 + TY == H);
    const bool xe0 = (tx0 == 0), xe1 = (tx0 + TX == W);

    for (int p = tid; p < 17 * 17; p += BLK) {
        const int bi = p / 17, bj = p - bi * 17;
        const int i0 = bi * 2, j0 = bj * 2;
        const bool slow = (ye0 && bi == 0) || (ye1 && bi == 16)
                       || (xe0 && bj == 0) || (xe1 && bj == 16);
        if (!slow) {
            float v[3][4][4];
            #pragma unroll
            for (int c = 0; c < 3; ++c)
                #pragma unroll
                for (int rr = 0; rr < 4; ++rr)
                    #pragma unroll
                    for (int cc = 0; cc < 4; ++cc)
                        v[c][rr][cc] = lat[c * LPS + (i0 + rr) * LRS + (j0 + cc)];
            #pragma unroll
            for (int a = 0; a < 2; ++a) {
                const int gy = ty0 - 1 + i0 + a;
                const float* ip = inp_n + ((size_t)gy * W + (tx0 - 1 + j0)) * 3;
                #pragma unroll
                for (int bb = 0; bb < 2; ++bb)
                    #pragma unroll
                    for (int c = 0; c < 3; ++c) {
                        float acc = 0.0f;
                        #pragma unroll
                        for (int dy = 0; dy < 3; ++dy)
                            #pragma unroll
                            for (int dx = 0; dx < 3; ++dx)
                                acc = fmaf(v[c][a + dy][bb + dx],
                                           gk[(dy * 3 + dx) * 3 + c], acc);
                        rbt[c * RPS + (i0 + a) * RRS + (j0 + bb)] =
                            ip[bb * 3 + c] * __builtin_amdgcn_rcpf(acc);
                    }
            }
        } else {
            #pragma unroll
            for (int a = 0; a < 2; ++a)
                #pragma unroll
                for (int bb = 0; bb < 2; ++bb) {
                    const int i = i0 + a, j = j0 + bb;
                    const int ry = refl(ty0 - 1 + i, H);
                    const int rx = refl(tx0 - 1 + j, W);
                    const int ti = ry - ty0 + 2, tj = rx - tx0 + 2;
                    const float* ip = inp_n + ((size_t)ry * W + rx) * 3;
                    #pragma unroll
                    for (int c = 0; c < 3; ++c) {
                        float acc = 0.0f;
                        #pragma unroll
                        for (int dy = -1; dy <= 1; ++dy)
                            #pragma unroll
                            for (int dx = -1; dx <= 1; ++dx)
                                acc = fmaf(lat[c * LPS + (ti + dy) * LRS + (tj + dx)],
                                           gk[((dy + 1) * 3 + (dx + 1)) * 3 + c], acc);
                        rbt[c * RPS + i * RRS + j] =
                            ip[c] * __builtin_amdgcn_rcpf(acc);
                    }
                }
        }
    }
    __syncthreads();

    // ---- out stage: exactly one 2x2 block per thread (16x16 blocks) ----
    const int oi0 = (tid >> 4) * 2, oj0 = (tid & 15) * 2;
    float r4[3][4][4];
    #pragma unroll
    for (int c = 0; c < 3; ++c)
        #pragma unroll
        for (int rr = 0; rr < 4; ++rr)
            #pragma unroll
            for (int cc = 0; cc < 4; ++cc)
                r4[c][rr][cc] = rbt[c * RPS + (oi0 + rr) * RRS + (oj0 + cc)];

    const int sdone = s_done;     // published by earlier barriers
    float esum = 0.0f;
    #pragma unroll
    for (int a = 0; a < 2; ++a) {
        float* op = lat_out + ((size_t)n * H * W + (size_t)(ty0 + oi0 + a) * W
                               + (tx0 + oj0)) * 3;
        #pragma unroll
        for (int bb = 0; bb < 2; ++bb)
            #pragma unroll
            for (int c = 0; c < 3; ++c) {
                float e = 0.0f;
                #pragma unroll
                for (int dy = 0; dy < 3; ++dy)
                    #pragma unroll
                    for (int dx = 0; dx < 3; ++dx)
                        e = fmaf(r4[c][a + dy][bb + dx],
                                 gkf[(dy * 3 + dx) * 3 + c], e);
                esum += e;
                if (!sdone)
                    op[bb * 3 + c] =
                        lat[c * LPS + (oi0 + a + 2) * LRS + (oj0 + bb + 2)] * e;
            }
    }

    // ---- block partial (plain store, double-buffered across dispatches) ----
    #pragma unroll
    for (int off = 32; off; off >>= 1) esum += __shfl_down(esum, off, 64);
    if (lane == 0) wred[wid] = esum;
    __syncthreads();
    if (tid == 0) part_wr[b] = wred[0] + wred[1] + wred[2] + wred[3];
}

extern "C" void kernel_launch(void* const* d_in, const int* in_sizes, int n_in,
                              void* d_out, int out_size, void* d_ws, size_t ws_size,
                              hipStream_t stream) {
    const float* inputs = (const float*)d_in[0];
    const float* kern   = (const float*)d_in[1];
    const float* kernf  = (const float*)d_in[2];
    float* latent = (float*)d_out;

    // ws: [0..3] done | [256..] partials A (1024 f32) | [+4096] partials B
    char* ws = (char*)d_ws;
    int*   done   = (int*)(ws + 0);
    float* part_a = (float*)(ws + 256);
    float* part_b = (float*)(ws + 256 + NBLKS * sizeof(float));

    for (int it = 0; it < ITERS; ++it) {
        const float* lat_src = (it == 0) ? inputs : latent;
        const float* prd = (it & 1) ? part_a : part_b;   // written by prev iter
        float*       pwr = (it & 1) ? part_b : part_a;
        rl_fused<<<NBLKS, BLK, 0, stream>>>(lat_src, inputs, kern, kernf,
                                            latent, prd, pwr, done,
                                            it > 0 ? 1 : 0);
    }
}